// Round 14
// baseline (671.630 us; speedup 1.0000x reference)
//
#include <hip/hip_runtime.h>
#include <hip/hip_cooperative_groups.h>
#include <math.h>

namespace cg = cooperative_groups;

#define NN 4096
#define NB 4
#define NITER 10
#define ROWS 16            // rows per block
#define TW 512             // 8 waves per block

typedef _Float16 f16x8 __attribute__((ext_vector_type(8)));
typedef float f32x4 __attribute__((ext_vector_type(4)));

// persistent scratch in module .bss — fully rewritten every call (deterministic)
__device__ __align__(16) float gA [NB * NN];
__device__ __align__(16) float gUx[NB * NN];
__device__ __align__(16) float gUy[NB * NN];
__device__ __align__(16) unsigned short gTh[2][12 * NN]; // ping-pong T^T as f16: [c][m]

__device__ inline unsigned short f16b(float x) {
    _Float16 h = (_Float16)x;
    return *(unsigned short*)&h;
}
__device__ inline unsigned f16pair(float x, float y) {
    return (unsigned)f16b(x) | ((unsigned)f16b(y) << 16);
}

// ---- stats + T^T(iter0) ----
__global__ __launch_bounds__(256) void stats_kernel(const float* __restrict__ dp,
                                                    const float* __restrict__ logits) {
    int i = blockIdx.x * 256 + threadIdx.x;          // 0..16383
    int b = i >> 12, n = i & 4095;
    float x = dp[2 * i], y = dp[2 * i + 1];
    float sq = x * x + y * y;
    float av = expf(-0.5f * sq);
    float inv = 1.0f / sqrtf(sq);
    float uxv = x * inv, uyv = y * inv;
    gA[i] = av; gUx[i] = uxv; gUy[i] = uyv;
    float l = logits[i];
    float mv = 2.0f / (1.0f + expf(-l)) - 1.0f;
    float t0 = av * mv;
    gTh[0][(3 * b + 0) * NN + n] = f16b(t0);
    gTh[0][(3 * b + 1) * NN + n] = f16b(t0 * uxv);
    gTh[0][(3 * b + 2) * NN + n] = f16b(t0 * uyv);
}

// ---- W_sym = (W+W^T)/2 -> packed f16 pairs; triangular tile pairs ----
__global__ __launch_bounds__(256) void wsym_kernel(const float* __restrict__ W,
                                                   unsigned* __restrict__ Sb) {
    __shared__ float At[64][65];
    __shared__ float Bt[64][65];
    int idx = blockIdx.x, bi = 0, rem = 64;
    while (idx >= rem) { idx -= rem; ++bi; --rem; }
    int bj = bi + idx;
    int r0 = threadIdx.x >> 4;                       // 0..15
    int c4 = (threadIdx.x & 15) * 4;                 // float col (x4)
#pragma unroll
    for (int i = 0; i < 4; ++i) {
        int r = r0 + i * 16;
        float4 va = *(const float4*)&W[(size_t)(bi * 64 + r) * NN + bj * 64 + c4];
        float4 vb = *(const float4*)&W[(size_t)(bj * 64 + r) * NN + bi * 64 + c4];
        At[r][c4 + 0] = va.x; At[r][c4 + 1] = va.y;
        At[r][c4 + 2] = va.z; At[r][c4 + 3] = va.w;
        Bt[r][c4 + 0] = vb.x; Bt[r][c4 + 1] = vb.y;
        Bt[r][c4 + 2] = vb.z; Bt[r][c4 + 3] = vb.w;
    }
    __syncthreads();
    int tp = threadIdx.x & 31;                       // column-pair index
    int rr = threadIdx.x >> 5;                       // 0..7
#pragma unroll
    for (int i = 0; i < 8; ++i) {
        int r = rr + i * 8;
        int c0 = 2 * tp, c1 = c0 + 1;
        float v0 = 0.5f * (At[r][c0] + Bt[c0][r]);
        float v1 = 0.5f * (At[r][c1] + Bt[c1][r]);
        Sb[(size_t)(bi * 64 + r) * 2048 + bj * 32 + tp] = f16pair(v0, v1);
        float u0 = 0.5f * (Bt[r][c0] + At[c0][r]);
        float u1 = 0.5f * (Bt[r][c1] + At[c1][r]);
        Sb[(size_t)(bj * 64 + r) * 2048 + bi * 32 + tp] = f16pair(u0, u1);
    }
}

// ---- persistent cooperative CRF loop: 256 blocks x 512 thr, 1 block/CU ----
// Per iter: stage T (R13-verified swizzle) -> MFMA (R13-verified core) ->
// reduce -> per-block T-update (distributed, no serial tail) -> grid.sync.
// W rows stay L2/L1-resident across iterations (no dispatch-boundary invalidation).
__global__ void __launch_bounds__(TW) crf_kernel(const unsigned short* __restrict__ Wh,
    const float* __restrict__ logits, float* __restrict__ out) {
    __shared__ __align__(16) unsigned short Tl[12 * NN];   // 96 KB
    __shared__ __align__(16) float Ered[8][64][4];         // 8 KB
    __shared__ float El[16][17];

    cg::grid_group grid = cg::this_grid();

    const int tid = threadIdx.x;
    const int w = tid >> 6, lane = tid & 63;
    const int mrow = lane & 15, grp = lane >> 4;
    const int row0 = blockIdx.x * ROWS;
    const int kbase = w * 512;                             // K-eighth per wave
    const unsigned short* Wp = Wh + (size_t)(row0 + mrow) * NN + kbase + grp * 8;
    const int cc = mrow;                                   // B col for this lane
    const bool cok = (cc < 12);
    const int gbase = cc * 512 + (kbase >> 3) + grp;

    unsigned short* Tcur = gTh[0];
    unsigned short* Tnxt = gTh[1];

    for (int it = 0; it < NITER; ++it) {
        // ---- stage T^T into LDS: granule (c, koct) at (c*512+koct)^(c&7) ----
#pragma unroll
        for (int c = 0; c < 12; ++c) {
            uint4 v = *(const uint4*)(Tcur + c * NN + tid * 8);
            int gs = (c * 512 + tid) ^ (c & 7);
            *(uint4*)(Tl + gs * 8) = v;
        }
        __syncthreads();

        f32x4 acc = {0.f, 0.f, 0.f, 0.f};
#pragma unroll
        for (int mf = 0; mf < 16; ++mf) {                  // 16 MFMAs, k step 32
            f16x8 a = *(const f16x8*)(Wp + mf * 32);
            f16x8 b = {};
            if (cok) {
                int gs = (gbase + mf * 4) ^ (cc & 7);
                b = *(const f16x8*)(Tl + gs * 8);
            }
            acc = __builtin_amdgcn_mfma_f32_16x16x32_f16(a, b, acc, 0, 0, 0);
        }
        *(f32x4*)Ered[w][lane] = acc;
        __syncthreads();

        // ---- reduce 8 waves, scatter to El[row][col] ----
        if (tid < 64) {
            f32x4 s = {};
#pragma unroll
            for (int ww = 0; ww < 8; ++ww) s += *(const f32x4*)Ered[ww][tid];
            int rr = tid >> 4, c = tid & 15;
#pragma unroll
            for (int r = 0; r < 4; ++r) El[rr * 4 + r][c] = s[r];
        }
        __syncthreads();

        // ---- fused update / final output for this block's 16 rows ----
        if (tid < 64) {
            int b = tid >> 4, r = tid & 15;
            int m = row0 + r, idx = b * NN + m;
            float S0 = El[r][3 * b], S1 = El[r][3 * b + 1], S2 = El[r][3 * b + 2];
            float av = gA[idx], uxv = gUx[idx], uyv = gUy[idx];
            float l = logits[idx] + av * (S0 - uxv * S1 - uyv * S2);
            if (it == NITER - 1) {
                out[idx] = l;
            } else {
                float mv = 2.0f / (1.0f + expf(-l)) - 1.0f;
                float t0 = av * mv;
                Tnxt[(3 * b + 0) * NN + m] = f16b(t0);
                Tnxt[(3 * b + 1) * NN + m] = f16b(t0 * uxv);
                Tnxt[(3 * b + 2) * NN + m] = f16b(t0 * uyv);
            }
        }

        if (it < NITER - 1) {
            __threadfence();                               // T writes device-visible
            grid.sync();                                   // all blocks' T complete
            unsigned short* tmp = Tcur; Tcur = Tnxt; Tnxt = tmp;
        }
    }
}

extern "C" void kernel_launch(void* const* d_in, const int* in_sizes, int n_in,
                              void* d_out, int out_size, void* d_ws, size_t ws_size,
                              hipStream_t stream) {
    const float* delta_p = (const float*)d_in[0];   // (4,64,64,2)
    const float* logits  = (const float*)d_in[1];   // (4,4096,1)
    const float* W       = (const float*)d_in[2];   // (1,4096,4096)
    float* out = (float*)d_out;

    unsigned* Wb = (unsigned*)d_ws;                  // 32 MiB packed f16 Wsym
    const unsigned short* Wh = (const unsigned short*)d_ws;

    stats_kernel<<<64, 256, 0, stream>>>(delta_p, logits);
    wsym_kernel<<<2080, 256, 0, stream>>>(W, Wb);    // 64*65/2 triangular tile pairs

    void* args[] = {(void*)&Wh, (void*)&logits, (void*)&out};
    hipLaunchCooperativeKernel((const void*)crf_kernel, dim3(256), dim3(TW),
                               args, 0, stream);
}

// Round 15
// 96.520 us; speedup vs baseline: 6.9585x; 6.9585x over previous
//
#include <hip/hip_runtime.h>
#include <math.h>

#define NN 4096
#define NB 4
#define NITER 10
#define ROWS 16            // rows per block
#define TW 512             // 8 waves per block
#define WSYM_BLOCKS 2080   // 64*65/2 triangular tile pairs

typedef _Float16 f16x8 __attribute__((ext_vector_type(8)));
typedef float f32x4 __attribute__((ext_vector_type(4)));

// persistent scratch in module .bss — fully rewritten every call (deterministic)
__device__ __align__(16) float gA [NB * NN];
__device__ __align__(16) float gUx[NB * NN];
__device__ __align__(16) float gUy[NB * NN];
__device__ __align__(16) unsigned short gTh[2][12 * NN]; // ping-pong T^T as f16: [c][m]

__device__ inline unsigned short f16b(float x) {
    _Float16 h = (_Float16)x;
    return *(unsigned short*)&h;
}
__device__ inline unsigned f16pair(float x, float y) {
    return (unsigned)f16b(x) | ((unsigned)f16b(y) << 16);
}

// ---- merged head: blocks [0,2080) symmetrize W -> f16; blocks [2080,2144) stats ----
__global__ __launch_bounds__(256) void head_kernel(const float* __restrict__ W,
    unsigned* __restrict__ Sb, const float* __restrict__ dp,
    const float* __restrict__ logits) {
    if (blockIdx.x >= WSYM_BLOCKS) {
        // ---- stats + T^T(iter0) ----
        int i = (blockIdx.x - WSYM_BLOCKS) * 256 + threadIdx.x;   // 0..16383
        int b = i >> 12, n = i & 4095;
        float x = dp[2 * i], y = dp[2 * i + 1];
        float sq = x * x + y * y;
        float av = expf(-0.5f * sq);
        float inv = 1.0f / sqrtf(sq);
        float uxv = x * inv, uyv = y * inv;
        gA[i] = av; gUx[i] = uxv; gUy[i] = uyv;
        float l = logits[i];
        float mv = 2.0f / (1.0f + expf(-l)) - 1.0f;
        float t0 = av * mv;
        gTh[0][(3 * b + 0) * NN + n] = f16b(t0);
        gTh[0][(3 * b + 1) * NN + n] = f16b(t0 * uxv);
        gTh[0][(3 * b + 2) * NN + n] = f16b(t0 * uyv);
        return;
    }
    // ---- W_sym = (W+W^T)/2 -> packed f16 pairs; triangular tile pairs ----
    __shared__ float At[64][65];
    __shared__ float Bt[64][65];
    int idx = blockIdx.x, bi = 0, rem = 64;
    while (idx >= rem) { idx -= rem; ++bi; --rem; }
    int bj = bi + idx;
    int r0 = threadIdx.x >> 4;                       // 0..15
    int c4 = (threadIdx.x & 15) * 4;                 // float col (x4)
#pragma unroll
    for (int i = 0; i < 4; ++i) {
        int r = r0 + i * 16;
        float4 va = *(const float4*)&W[(size_t)(bi * 64 + r) * NN + bj * 64 + c4];
        float4 vb = *(const float4*)&W[(size_t)(bj * 64 + r) * NN + bi * 64 + c4];
        At[r][c4 + 0] = va.x; At[r][c4 + 1] = va.y;
        At[r][c4 + 2] = va.z; At[r][c4 + 3] = va.w;
        Bt[r][c4 + 0] = vb.x; Bt[r][c4 + 1] = vb.y;
        Bt[r][c4 + 2] = vb.z; Bt[r][c4 + 3] = vb.w;
    }
    __syncthreads();
    int tp = threadIdx.x & 31;                       // column-pair index
    int rr = threadIdx.x >> 5;                       // 0..7
#pragma unroll
    for (int i = 0; i < 8; ++i) {
        int r = rr + i * 8;
        int c0 = 2 * tp, c1 = c0 + 1;
        float v0 = 0.5f * (At[r][c0] + Bt[c0][r]);
        float v1 = 0.5f * (At[r][c1] + Bt[c1][r]);
        Sb[(size_t)(bi * 64 + r) * 2048 + bj * 32 + tp] = f16pair(v0, v1);
        float u0 = 0.5f * (Bt[r][c0] + At[c0][r]);
        float u1 = 0.5f * (Bt[r][c1] + At[c1][r]);
        Sb[(size_t)(bj * 64 + r) * 2048 + bi * 32 + tp] = f16pair(u0, u1);
    }
}

// ---- fused MFMA matvec + update: block owns 16 rows x full K ----
// Per-wave T staging: wave w consumes only k in [w*512, w*512+512) — stage that
// 12 KB slice into a wave-PRIVATE LDS region. No block barrier before MFMA
// (wave-synchronous ds_write -> ds_read; compiler emits the lgkmcnt wait).
// A-fragments prefetched to registers first so the W stream is in flight from
// cycle 0.  A: lane&15=row, 8 consecutive k.  B: lane&15=col, 8 consecutive k.
// D: col=lane&15, row=(lane>>4)*4+reg  [verified m91 mapping, R10/R13 passing].
__global__ void __launch_bounds__(TW) matvec_kernel(const unsigned short* __restrict__ Wh,
    const float* __restrict__ logits, float* __restrict__ out, int rd, int last) {
    __shared__ __align__(16) unsigned short Tl[8][12 * 512]; // 96 KB, per-wave slices
    __shared__ __align__(16) float Ered[8][64][4];           // 8 KB
    __shared__ float El[16][17];

    const int tid = threadIdx.x;
    const int w = tid >> 6, lane = tid & 63;
    const int mrow = lane & 15, grp = lane >> 4;
    const int row0 = blockIdx.x * ROWS;
    const int kbase = w * 512;                             // K-eighth per wave
    const unsigned short* Wp = Wh + (size_t)(row0 + mrow) * NN + kbase + grp * 8;
    const int cc = mrow;                                   // B col for this lane
    const bool cok = (cc < 12);
    const unsigned short* Tcur = gTh[rd];

    // ---- prefetch all 16 A-fragments (W stream starts immediately) ----
    f16x8 areg[16];
#pragma unroll
    for (int mf = 0; mf < 16; ++mf) areg[mf] = *(const f16x8*)(Wp + mf * 32);

    // ---- per-wave stage of own T slice: granule (c,j) -> (c*64+j)^(c&7) ----
    unsigned short* Tw = &Tl[w][0];
#pragma unroll
    for (int c = 0; c < 12; ++c) {
        uint4 v = *(const uint4*)(Tcur + c * NN + kbase + lane * 8);
        int g = (c * 64 + lane) ^ (c & 7);
        *(uint4*)(Tw + g * 8) = v;
    }

    f32x4 acc = {0.f, 0.f, 0.f, 0.f};
#pragma unroll
    for (int mf = 0; mf < 16; ++mf) {                      // 16 MFMAs, k step 32
        f16x8 b = {};
        if (cok) {
            int g = (cc * 64 + mf * 4 + grp) ^ (cc & 7);
            b = *(const f16x8*)(Tw + g * 8);
        }
        acc = __builtin_amdgcn_mfma_f32_16x16x32_f16(areg[mf], b, acc, 0, 0, 0);
    }
    *(f32x4*)Ered[w][lane] = acc;
    __syncthreads();

    // ---- reduce 8 waves, scatter to El[row][col] ----
    if (tid < 64) {
        f32x4 s = {};
#pragma unroll
        for (int ww = 0; ww < 8; ++ww) s += *(const f32x4*)Ered[ww][tid];
        int rr = tid >> 4, c = tid & 15;
#pragma unroll
        for (int r = 0; r < 4; ++r) El[rr * 4 + r][c] = s[r];
    }
    __syncthreads();

    // ---- fused update / final output for this block's 16 rows ----
    if (tid < 64) {
        int b = tid >> 4, r = tid & 15;
        int m = row0 + r, idx = b * NN + m;
        float S0 = El[r][3 * b], S1 = El[r][3 * b + 1], S2 = El[r][3 * b + 2];
        float av = gA[idx], uxv = gUx[idx], uyv = gUy[idx];
        float l = logits[idx] + av * (S0 - uxv * S1 - uyv * S2);
        if (last) {
            out[idx] = l;
        } else {
            float mv = 2.0f / (1.0f + expf(-l)) - 1.0f;
            float t0 = av * mv;
            unsigned short* Td = gTh[rd ^ 1];
            Td[(3 * b + 0) * NN + m] = f16b(t0);
            Td[(3 * b + 1) * NN + m] = f16b(t0 * uxv);
            Td[(3 * b + 2) * NN + m] = f16b(t0 * uyv);
        }
    }
}

extern "C" void kernel_launch(void* const* d_in, const int* in_sizes, int n_in,
                              void* d_out, int out_size, void* d_ws, size_t ws_size,
                              hipStream_t stream) {
    const float* delta_p = (const float*)d_in[0];   // (4,64,64,2)
    const float* logits  = (const float*)d_in[1];   // (4,4096,1)
    const float* W       = (const float*)d_in[2];   // (1,4096,4096)
    float* out = (float*)d_out;

    unsigned* Wb = (unsigned*)d_ws;                  // 32 MiB packed f16 Wsym
    const unsigned short* Wh = (const unsigned short*)d_ws;

    head_kernel<<<WSYM_BLOCKS + 64, 256, 0, stream>>>(W, Wb, delta_p, logits);

    for (int it = 0; it < NITER; ++it)
        matvec_kernel<<<256, TW, 0, stream>>>(Wh, logits, out, it & 1,
                                              it == NITER - 1 ? 1 : 0);
}